// Round 11
// baseline (132.686 us; speedup 1.0000x reference)
//
#include <hip/hip_runtime.h>
#include <hip/hip_bf16.h>
#include <cstdint>

#define Bc 2
#define Nc 3072
#define Hc 4
#define NW32 96      // 32-key tiles per row
#define TILEB 8192   // per 32-key fp16 image tile: K 4KB | V 4KB
#define KSC 4        // key splits
#define TPS (NW32/KSC)   // 24 tiles per split

typedef __bf16    bf16x8 __attribute__((ext_vector_type(8)));
typedef _Float16  f16x8  __attribute__((ext_vector_type(8)));
typedef float     f32x16 __attribute__((ext_vector_type(16)));

#define QSCALE 0.18033688f   // 0.125 * log2(e): exp(s/8) == exp2(s*QSCALE)

static __device__ __forceinline__ f32x16 mfma32bf(bf16x8 a, bf16x8 b, f32x16 c) {
    return __builtin_amdgcn_mfma_f32_32x32x16_bf16(a, b, c, 0, 0, 0);
}
static __device__ __forceinline__ f32x16 mfma32h(f16x8 a, f16x8 b, f32x16 c) {
    return __builtin_amdgcn_mfma_f32_32x32x16_f16(a, b, c, 0, 0, 0);
}
static __device__ __forceinline__ void gload_lds16(const void* g, void* l) {
    __builtin_amdgcn_global_load_lds((const __attribute__((address_space(1))) void*)g,
                                     (__attribute__((address_space(3))) void*)l, 16, 0, 0);
}
static __device__ __forceinline__ uint32_t pkrtz(float lo, float hi) {
    uint32_t w;
    asm("v_cvt_pkrtz_f16_f32 %0, %1, %2" : "=v"(w) : "v"(lo), "v"(hi));
    return w;
}

// softmax for one 32-key sub-tile (16 scores/lane): leaky+exp2, pack, mask packed word
static __device__ __forceinline__ void softmax_pack(const f32x16& sc, uint32_t mwh,
                                                    uint32_t W8[8])
{
    #pragma unroll
    for (int i = 0; i < 8; ++i) {
        const int bp0 = (2*i & 3) + 8*(2*i >> 2);   // bp1 = bp0+1
        float s0 = sc[2*i], s1 = sc[2*i + 1];
        float a0 = fmaxf(s0, 0.2f*s0);
        float a1 = fmaxf(s1, 0.2f*s1);
        float e0, e1;
        asm("v_exp_f32 %0, %1" : "=v"(e0) : "v"(a0));   // exp2 (log2e pre-folded)
        asm("v_exp_f32 %0, %1" : "=v"(e1) : "v"(a1));
        uint32_t pk = pkrtz(e0, e1);
        uint32_t m0 = (uint32_t)(((int)(mwh << (31 - bp0))) >> 31);
        uint32_t m1 = (uint32_t)(((int)(mwh << (30 - bp0))) >> 31);
        W8[i] = pk & ((m0 & 0x0000ffffu) | (m1 & 0xffff0000u));
    }
}

static __device__ __forceinline__ void assemble_pa(uint32_t W8[8], f16x8& pa0, f16x8& pa1)
{
    uint32_t a0 = W8[0], a2 = W8[2], a1 = W8[1], a3 = W8[3];
    uint32_t b0 = W8[4], b2 = W8[6], b1 = W8[5], b3 = W8[7];
    asm("v_permlane32_swap_b32 %0, %1" : "+v"(a0), "+v"(a2));
    asm("v_permlane32_swap_b32 %0, %1" : "+v"(a1), "+v"(a3));
    asm("v_permlane32_swap_b32 %0, %1" : "+v"(b0), "+v"(b2));
    asm("v_permlane32_swap_b32 %0, %1" : "+v"(b1), "+v"(b3));
    union { uint32_t u[4]; f16x8 v; } u0, u1;
    u0.u[0] = a0; u0.u[1] = a1; u0.u[2] = a2; u0.u[3] = a3;
    u1.u[0] = b0; u1.u[1] = b1; u1.u[2] = b2; u1.u[3] = b3;
    pa0 = u0.v; pa1 = u1.v;
}

// ---- prep: W -> bf16 hi/lo [p][h][o][d] (+scaled bias) ----
__global__ void prep_kernel(const float* __restrict__ Wq, const float* __restrict__ Wk,
                            const float* __restrict__ Wv,
                            const float* __restrict__ bq, const float* __restrict__ bk,
                            const float* __restrict__ bv,
                            __bf16* __restrict__ Wbh, __bf16* __restrict__ Wbl,
                            float* __restrict__ Bs)
{
    int i = blockIdx.x*256 + threadIdx.x;   // 49152
    int d = i & 63, o = (i >> 6) & 63, h = (i >> 12) & 3, p = i >> 14;
    const float* W = (p == 0) ? Wq : (p == 1) ? Wk : Wv;
    float scale = (p == 0) ? QSCALE : 1.0f;
    float val = W[(h*64 + d)*64 + o] * scale;
    int idx = (((p*Hc + h)*64 + o) << 6) + d;
    __bf16 hi = (__bf16)val;
    Wbh[idx] = hi;
    Wbl[idx] = (__bf16)(val - (float)hi);
    if (i < 3*Hc*64) {
        int pp = i / (Hc*64), rest = i % (Hc*64);
        const float* B = (pp == 0) ? bq : (pp == 1) ? bk : bv;
        Bs[i] = B[rest] * ((pp == 0) ? QSCALE : 1.0f);
    }
}

// ---- QKV projection via MFMA (split-bf16, x converted in-register).
//      Q,K -> fp16 flat [bh][n][64]; V -> image granules fp16 ----
__global__ __launch_bounds__(256) void qkv_mfma(
    const float* __restrict__ x,
    const __bf16* __restrict__ Wbh, const __bf16* __restrict__ Wbl,
    const float* __restrict__ Bs,
    _Float16* __restrict__ Qf, _Float16* __restrict__ Kf,
    _Float16* __restrict__ KVimg)
{
    const int lane = threadIdx.x & 63, w = threadIdx.x >> 6;
    const int l31 = lane & 31, hi = lane >> 5;
    int t = blockIdx.x;                 // 1152 blocks
    int nt = t % 48; t /= 48;
    int b  = t & 1;  t >>= 1;
    int p  = t % 3;
    int h  = t / 3;
    const int r0 = (w >> 1)*32, c0 = (w & 1)*32, n0 = nt*64;

    bf16x8 xh[4], xl[4], wh[4], wl[4];
    #pragma unroll
    for (int kk = 0; kk < 4; ++kk) {
        size_t xoff = (((size_t)(b*Nc + n0 + r0 + l31)) << 6) + kk*16 + hi*8;
        float4 f0 = *(const float4*)(x + xoff);
        float4 f1 = *(const float4*)(x + xoff + 4);
        float xs[8] = {f0.x, f0.y, f0.z, f0.w, f1.x, f1.y, f1.z, f1.w};
        #pragma unroll
        for (int j = 0; j < 8; ++j) {
            __bf16 hh = (__bf16)xs[j];
            xh[kk][j] = hh;
            xl[kk][j] = (__bf16)(xs[j] - (float)hh);
        }
        size_t woff = (((size_t)((p*Hc + h)*64 + c0 + l31)) << 6) + kk*16 + hi*8;
        wh[kk] = *(const bf16x8*)(Wbh + woff);
        wl[kk] = *(const bf16x8*)(Wbl + woff);
    }
    float bias = Bs[(p*Hc + h)*64 + c0 + l31];
    f32x16 acc;
    #pragma unroll
    for (int i = 0; i < 16; ++i) acc[i] = bias;
    #pragma unroll
    for (int kk = 0; kk < 4; ++kk) {
        acc = mfma32bf(xh[kk], wh[kk], acc);
        acc = mfma32bf(xl[kk], wh[kk], acc);
        acc = mfma32bf(xh[kk], wl[kk], acc);
    }
    const int bh = b*Hc + h;
    if (p < 2) {
        _Float16* dst = (p == 0) ? Qf : Kf;
        #pragma unroll
        for (int r = 0; r < 16; ++r) {
            int row = (r & 3) + 8*(r >> 2) + 4*hi;
            size_t idx = (((size_t)bh*Nc + n0 + r0 + row) << 6) + c0 + l31;
            dst[idx] = (_Float16)acc[r];
        }
    } else {
        // V image granule (kb,o) = V[kb*8..+7][o], fp16
        const int t_img = (n0 + r0) >> 5;
        char* img = (char*)KVimg + (size_t)(bh*96 + t_img)*TILEB;
        #pragma unroll
        for (int grp = 0; grp < 2; ++grp) {
            uint32_t wH[4];
            #pragma unroll
            for (int j = 0; j < 4; ++j)
                wH[j] = pkrtz(acc[grp*8 + 2*j], acc[grp*8 + 2*j + 1]);
            asm("v_permlane32_swap_b32 %0, %1" : "+v"(wH[0]), "+v"(wH[2]));
            asm("v_permlane32_swap_b32 %0, %1" : "+v"(wH[1]), "+v"(wH[3]));
            const int kb = grp*2 + hi;
            const int o  = c0 + l31;
            uint4 gh = {wH[0], wH[1], wH[2], wH[3]};
            *(uint4*)(img + 4096 + ((kb*64 + o) << 4)) = gh;
        }
    }
}

// ---- K image: granule (dc,key) = K[key][dc*8..+7] fp16, at tile offset 0 ----
__global__ void imgk_kernel(const _Float16* __restrict__ Kf, _Float16* __restrict__ KVimg)
{
    const int t = blockIdx.x % 96, bh = blockIdx.x / 96;
    char* img = (char*)KVimg + (size_t)(bh*96 + t)*TILEB;
    int dc = threadIdx.x & 7, key = threadIdx.x >> 3;
    size_t src = (((size_t)bh*Nc + t*32 + key) << 6) + dc*8;
    *(uint4*)(img + (dc*32 + key)*16) = *(const uint4*)(Kf + src);
}

// ---- pack adjacency transposed: pmT[b][w][n], bit j = edge[b][n][32w+j] ----
__global__ void pack_kernel(const int* __restrict__ edge, uint32_t* __restrict__ pmT)
{
    int gw = blockIdx.x*4 + (threadIdx.x >> 6);
    int lane = threadIdx.x & 63;
    int ng = gw % 48; gw /= 48;
    int w  = gw % NW32; gw /= NW32;
    int b  = gw;
    int n = ng*64 + lane;
    const uint4* ep = (const uint4*)(edge + ((size_t)b*Nc + n)*Nc + w*32);
    uint32_t word = 0;
    #pragma unroll
    for (int i = 0; i < 8; ++i) {
        uint4 e = ep[i];
        word |= (e.x ? 1u : 0u) << (4*i);
        word |= (e.y ? 1u : 0u) << (4*i + 1);
        word |= (e.z ? 1u : 0u) << (4*i + 2);
        word |= (e.w ? 1u : 0u) << (4*i + 3);
    }
    pmT[((size_t)b*NW32 + w)*Nc + n] = word;
}

// ---- flash attention fp16: 8 waves = 4 q-groups x 2 key-halves, 24 waves/CU,
//      3-buffer single-barrier pipeline (outer unroll 1 x inner static 3),
//      compiler-fenced barriers, ones-MFMA denominator ----
__global__ __launch_bounds__(512, 6) void attn_mfma(
    const _Float16* __restrict__ Qf,
    const _Float16* __restrict__ KVimg, const uint32_t* __restrict__ pmT,
    float* __restrict__ PA, float* __restrict__ PL)
{
    __shared__ __align__(16) char lds[3][2*TILEB];   // 48 KB
    const int lane = threadIdx.x & 63, w = threadIdx.x >> 6;  // w in [0,8)
    const int l31 = lane & 31, hi = lane >> 5;
    const int p2 = w >> 1;        // q-group
    const int u  = w & 1;         // key-half (32-key subtile)
    int gb = blockIdx.x;
    const int bh = gb & 7; gb >>= 3;        // XCD swizzle: one bh per XCD
    const int qt = gb % 24;
    const int ks = gb / 24;
    const int b = gb >= 0 ? (bh >> 2) : 0;
    const int qrow0 = qt*128 + p2*32;
    const int t0 = ks*TPS;                  // in 32-key tiles

    // mask pointer for this wave's subtile sequence (tiles t0+u, t0+u+2, ...)
    const uint32_t* pmp = pmT + ((size_t)b*NW32 + t0 + u)*Nc + qrow0 + l31;
    uint32_t mw_cur = pmp[0];
    __builtin_amdgcn_sched_barrier(0);
    const char* gbase = (const char*)KVimg + (size_t)(bh*96 + t0)*TILEB
                      + w*2048 + lane*16;
    #pragma unroll
    for (int g = 0; g < 2; ++g)
        gload_lds16(gbase + g*1024, &lds[0][w*2048 + g*1024]);

    // Q B-frags (col = q-row = l31, k = d), pre-scaled by QSCALE, fp16
    f16x8 qf[4];
    #pragma unroll
    for (int kk = 0; kk < 4; ++kk) {
        size_t qoff = (((size_t)bh*Nc + qrow0 + l31) << 6) + kk*16 + hi*8;
        qf[kk] = *(const f16x8*)(Qf + qoff);
    }
    f16x8 ones;
    #pragma unroll
    for (int j = 0; j < 8; ++j) ones[j] = (_Float16)1.0f;
    f32x16 fzero;
    #pragma unroll
    for (int i = 0; i < 16; ++i) fzero[i] = 0.f;

    f32x16 acc0 = fzero, acc1 = fzero, acc2 = fzero;

    #pragma unroll 1
    for (int s = 0; s < 4; ++s) {
        #pragma unroll
        for (int j = 0; j < 3; ++j) {
            // prefetch next pair-tile (always; final one is a harmless in-workspace
            // over-read that is drained before epilogue and never consumed)
            uint32_t mw_next = pmp[(size_t)(j + 1)*2*Nc];
            __builtin_amdgcn_sched_barrier(0);
            {
                char* ldst = &lds[(j + 1) % 3][w*2048];
                const char* gs = gbase + (size_t)(j + 1)*2*TILEB;
                #pragma unroll
                for (int g = 0; g < 2; ++g)
                    gload_lds16(gs + g*1024, ldst + g*1024);
            }
            asm volatile("s_waitcnt vmcnt(3)" ::: "memory");
            __builtin_amdgcn_s_barrier();
            asm volatile("" ::: "memory");   // fence: no LDS reads hoist above barrier
            const char* Lb = &lds[j][u*TILEB];

            // ---- QK^T: 4 MFMA (C=0 seed) ----
            f32x16 sc;
            __builtin_amdgcn_s_setprio(1);
            {
                f16x8 k0 = *(const f16x8*)(Lb + (hi << 9) + (l31 << 4));
                sc = mfma32h(k0, qf[0], fzero);
            }
            #pragma unroll
            for (int kk = 1; kk < 4; ++kk) {
                f16x8 k0 = *(const f16x8*)(Lb + ((kk*2 + hi) << 9) + (l31 << 4));
                sc = mfma32h(k0, qf[kk], sc);
            }
            __builtin_amdgcn_s_setprio(0);

            // ---- softmax -> masked packed fp16 pairs ----
            uint32_t W8[8];
            softmax_pack(sc, mw_cur >> (hi*4), W8);
            mw_cur = mw_next;
            f16x8 pa0, pa1;
            assemble_pa(W8, pa0, pa1);

            // ---- denominator (2 MFMA, ones) + PV (4 MFMA) ----
            __builtin_amdgcn_s_setprio(1);
            acc2 = mfma32h(pa0, ones, acc2);
            acc2 = mfma32h(pa1, ones, acc2);
            #pragma unroll
            for (int kkp = 0; kkp < 2; ++kkp) {
                f16x8 pa = kkp ? pa1 : pa0;
                #pragma unroll
                for (int ot = 0; ot < 2; ++ot) {
                    f16x8 vh = *(const f16x8*)(Lb + 4096 + ((kkp*2 + hi) << 10)
                                               + ((ot*32 + l31) << 4));
                    if (ot == 0) acc0 = mfma32h(pa, vh, acc0);
                    else         acc1 = mfma32h(pa, vh, acc1);
                }
            }
            __builtin_amdgcn_s_setprio(0);
            asm volatile("" ::: "memory");   // fence: no LDS reads sink below this iter
        }
        pmp   += (size_t)6*Nc;
        gbase += (size_t)6*TILEB;
    }

    // drain dangling prefetch DMA before reusing LDS for the combine
    asm volatile("s_waitcnt vmcnt(0)" ::: "memory");
    __syncthreads();

    // ---- wave-pair combine (key-halves) via LDS, then store ----
    float* xb = (float*)&lds[0][0];          // [48][256] floats = 48KB
    if (u) {
        #pragma unroll
        for (int r = 0; r < 16; ++r) {
            xb[(r)      *256 + p2*64 + lane] = acc0[r];
            xb[(16 + r) *256 + p2*64 + lane] = acc1[r];
            xb[(32 + r) *256 + p2*64 + lane] = acc2[r];
        }
    }
    __syncthreads();
    if (!u) {
        #pragma unroll
        for (int r = 0; r < 16; ++r) {
            acc0[r] += xb[(r)      *256 + p2*64 + lane];
            acc1[r] += xb[(16 + r) *256 + p2*64 + lane];
            acc2[r] += xb[(32 + r) *256 + p2*64 + lane];
        }
        float* po = PA + (((size_t)(bh*KSC + ks)*Nc + qrow0) << 6);
        #pragma unroll
        for (int r = 0; r < 16; ++r) {
            int row = (r & 3) + 8*(r >> 2) + 4*hi;
            po[((size_t)row << 6) + l31]      = acc0[r];
            po[((size_t)row << 6) + 32 + l31] = acc1[r];
        }
        if (l31 == 0) {
            float* pl = PL + (size_t)(bh*KSC + ks)*Nc + qrow0;
            #pragma unroll
            for (int r = 0; r < 16; ++r)
                pl[(r & 3) + 8*(r >> 2) + 4*hi] = acc2[r];
        }
    }
}

// ---- merge: sum key-splits, divide, mean heads, leaky ----
__global__ void merge_kernel(const float* __restrict__ PA, const float* __restrict__ PL,
                             float* __restrict__ out)
{
    int gid = blockIdx.x*256 + threadIdx.x;
    int o  = gid & 63;
    int bn = gid >> 6;
    int n  = bn % Nc;
    int b  = bn / Nc;
    float ft = 0.f;
    for (int h = 0; h < Hc; ++h) {
        int bh = b*Hc + h;
        float A = 0.f, L = 0.f;
        for (int ks = 0; ks < KSC; ++ks) {
            A += PA[(((size_t)(bh*KSC + ks)*Nc + n) << 6) + o];
            L += PL[(size_t)(bh*KSC + ks)*Nc + n];
        }
        ft += A / L;
    }
    ft *= 0.25f;
    out[((size_t)bn << 6) + o] = fmaxf(ft, 0.f) + 0.2f*fminf(ft, 0.f);
}

extern "C" void kernel_launch(void* const* d_in, const int* in_sizes, int n_in,
                              void* d_out, int out_size, void* d_ws, size_t ws_size,
                              hipStream_t stream)
{
    const float* x    = (const float*)d_in[0];
    const int*   edge = (const int*)d_in[1];
    const float* Wv   = (const float*)d_in[2];
    const float* bv   = (const float*)d_in[3];
    const float* Wq   = (const float*)d_in[4];
    const float* bq   = (const float*)d_in[5];
    const float* Wk   = (const float*)d_in[6];
    const float* bk   = (const float*)d_in[7];
    float* out = (float*)d_out;

    const size_t PROJ = (size_t)Bc*Hc*Nc*64;
    char* p = (char*)d_ws;
    __bf16* Wbh = (__bf16*)p;     p += 49152*2;
    __bf16* Wbl = (__bf16*)p;     p += 49152*2;
    float*  Bs  = (float*)p;      p += 4096;
    _Float16* Qf = (_Float16*)p;  p += PROJ*2;
    _Float16* Kf = (_Float16*)p;  p += PROJ*2;
    _Float16* KVimg = (_Float16*)p; p += (size_t)Bc*Hc*96*TILEB;
    uint32_t* pmT = (uint32_t*)p; p += (size_t)Bc*NW32*Nc*4;
    float* PA = (float*)p;        p += (size_t)Bc*Hc*KSC*Nc*64*4;
    float* PL = (float*)p;

    hipLaunchKernelGGL(prep_kernel, dim3(192),  dim3(256), 0, stream,
                       Wq, Wk, Wv, bq, bk, bv, Wbh, Wbl, Bs);
    hipLaunchKernelGGL(qkv_mfma,    dim3(1152), dim3(256), 0, stream,
                       x, Wbh, Wbl, Bs, Qf, Kf, KVimg);
    hipLaunchKernelGGL(imgk_kernel, dim3(Bc*Hc*96), dim3(256), 0, stream, Kf, KVimg);
    hipLaunchKernelGGL(pack_kernel, dim3(Bc*NW32*48/4), dim3(256), 0, stream, edge, pmT);
    hipLaunchKernelGGL(attn_mfma,   dim3(8*KSC*24), dim3(512), 0, stream,
                       Qf, KVimg, pmT, PA, PL);
    hipLaunchKernelGGL(merge_kernel, dim3((Bc*Nc*64)/256), dim3(256), 0, stream,
                       PA, PL, out);
}

// Round 12
// 78.442 us; speedup vs baseline: 1.6915x; 1.6915x over previous
//
#include <hip/hip_runtime.h>
#include <hip/hip_bf16.h>
#include <cstdint>

#define Bc 2
#define Nc 3072
#define Hc 4
#define NW32 96      // 32-key tiles per row
#define TILEB 8192   // per 32-key fp16 image tile: K 4KB | V 4KB
#define KSC 4        // key splits
#define TPS (NW32/KSC)   // 24 tiles per split

typedef __bf16    bf16x8 __attribute__((ext_vector_type(8)));
typedef _Float16  f16x8  __attribute__((ext_vector_type(8)));
typedef float     f32x16 __attribute__((ext_vector_type(16)));

#define QSCALE 0.18033688f   // 0.125 * log2(e): exp(s/8) == exp2(s*QSCALE)

static __device__ __forceinline__ f32x16 mfma32bf(bf16x8 a, bf16x8 b, f32x16 c) {
    return __builtin_amdgcn_mfma_f32_32x32x16_bf16(a, b, c, 0, 0, 0);
}
static __device__ __forceinline__ f32x16 mfma32h(f16x8 a, f16x8 b, f32x16 c) {
    return __builtin_amdgcn_mfma_f32_32x32x16_f16(a, b, c, 0, 0, 0);
}
static __device__ __forceinline__ void gload_lds16(const void* g, void* l) {
    __builtin_amdgcn_global_load_lds((const __attribute__((address_space(1))) void*)g,
                                     (__attribute__((address_space(3))) void*)l, 16, 0, 0);
}
static __device__ __forceinline__ uint32_t pkrtz(float lo, float hi) {
    uint32_t w;
    asm("v_cvt_pkrtz_f16_f32 %0, %1, %2" : "=v"(w) : "v"(lo), "v"(hi));
    return w;
}

// softmax for one 32-key sub-tile (16 scores/lane): leaky+exp2, mask floats,
// VALU denominator from the same masked values, pack to fp16 pairs
static __device__ __forceinline__ void softmax_pack(const f32x16& sc, uint32_t mwh,
                                                    uint32_t W8[8], float& lsum)
{
    #pragma unroll
    for (int i = 0; i < 8; ++i) {
        const int bp0 = (2*i & 3) + 8*(2*i >> 2);   // bp1 = bp0+1
        float s0 = sc[2*i], s1 = sc[2*i + 1];
        float a0 = fmaxf(s0, 0.2f*s0);
        float a1 = fmaxf(s1, 0.2f*s1);
        float e0, e1;
        asm("v_exp_f32 %0, %1" : "=v"(e0) : "v"(a0));   // exp2 (log2e pre-folded)
        asm("v_exp_f32 %0, %1" : "=v"(e1) : "v"(a1));
        uint32_t m0 = (uint32_t)(((int)(mwh << (31 - bp0))) >> 31);
        uint32_t m1 = (uint32_t)(((int)(mwh << (30 - bp0))) >> 31);
        float p0 = __uint_as_float(__float_as_uint(e0) & m0);
        float p1 = __uint_as_float(__float_as_uint(e1) & m1);
        lsum += p0 + p1;
        W8[i] = pkrtz(p0, p1);
    }
}

static __device__ __forceinline__ void assemble_pa(uint32_t W8[8], f16x8& pa0, f16x8& pa1)
{
    uint32_t a0 = W8[0], a2 = W8[2], a1 = W8[1], a3 = W8[3];
    uint32_t b0 = W8[4], b2 = W8[6], b1 = W8[5], b3 = W8[7];
    asm("v_permlane32_swap_b32 %0, %1" : "+v"(a0), "+v"(a2));
    asm("v_permlane32_swap_b32 %0, %1" : "+v"(a1), "+v"(a3));
    asm("v_permlane32_swap_b32 %0, %1" : "+v"(b0), "+v"(b2));
    asm("v_permlane32_swap_b32 %0, %1" : "+v"(b1), "+v"(b3));
    union { uint32_t u[4]; f16x8 v; } u0, u1;
    u0.u[0] = a0; u0.u[1] = a1; u0.u[2] = a2; u0.u[3] = a3;
    u1.u[0] = b0; u1.u[1] = b1; u1.u[2] = b2; u1.u[3] = b3;
    pa0 = u0.v; pa1 = u1.v;
}

// ---- prep: W -> bf16 hi/lo [p][h][o][d] (+scaled bias) ----
__global__ void prep_kernel(const float* __restrict__ Wq, const float* __restrict__ Wk,
                            const float* __restrict__ Wv,
                            const float* __restrict__ bq, const float* __restrict__ bk,
                            const float* __restrict__ bv,
                            __bf16* __restrict__ Wbh, __bf16* __restrict__ Wbl,
                            float* __restrict__ Bs)
{
    int i = blockIdx.x*256 + threadIdx.x;   // 49152
    int d = i & 63, o = (i >> 6) & 63, h = (i >> 12) & 3, p = i >> 14;
    const float* W = (p == 0) ? Wq : (p == 1) ? Wk : Wv;
    float scale = (p == 0) ? QSCALE : 1.0f;
    float val = W[(h*64 + d)*64 + o] * scale;
    int idx = (((p*Hc + h)*64 + o) << 6) + d;
    __bf16 hi = (__bf16)val;
    Wbh[idx] = hi;
    Wbl[idx] = (__bf16)(val - (float)hi);
    if (i < 3*Hc*64) {
        int pp = i / (Hc*64), rest = i % (Hc*64);
        const float* B = (pp == 0) ? bq : (pp == 1) ? bk : bv;
        Bs[i] = B[rest] * ((pp == 0) ? QSCALE : 1.0f);
    }
}

// ---- QKV projection via MFMA (split-bf16, x converted in-register).
//      Q,K -> fp16 flat [bh][n][64]; V -> image granules fp16 ----
__global__ __launch_bounds__(256) void qkv_mfma(
    const float* __restrict__ x,
    const __bf16* __restrict__ Wbh, const __bf16* __restrict__ Wbl,
    const float* __restrict__ Bs,
    _Float16* __restrict__ Qf, _Float16* __restrict__ Kf,
    _Float16* __restrict__ KVimg)
{
    const int lane = threadIdx.x & 63, w = threadIdx.x >> 6;
    const int l31 = lane & 31, hi = lane >> 5;
    int t = blockIdx.x;                 // 1152 blocks
    int nt = t % 48; t /= 48;
    int b  = t & 1;  t >>= 1;
    int p  = t % 3;
    int h  = t / 3;
    const int r0 = (w >> 1)*32, c0 = (w & 1)*32, n0 = nt*64;

    bf16x8 xh[4], xl[4], wh[4], wl[4];
    #pragma unroll
    for (int kk = 0; kk < 4; ++kk) {
        size_t xoff = (((size_t)(b*Nc + n0 + r0 + l31)) << 6) + kk*16 + hi*8;
        float4 f0 = *(const float4*)(x + xoff);
        float4 f1 = *(const float4*)(x + xoff + 4);
        float xs[8] = {f0.x, f0.y, f0.z, f0.w, f1.x, f1.y, f1.z, f1.w};
        #pragma unroll
        for (int j = 0; j < 8; ++j) {
            __bf16 hh = (__bf16)xs[j];
            xh[kk][j] = hh;
            xl[kk][j] = (__bf16)(xs[j] - (float)hh);
        }
        size_t woff = (((size_t)((p*Hc + h)*64 + c0 + l31)) << 6) + kk*16 + hi*8;
        wh[kk] = *(const bf16x8*)(Wbh + woff);
        wl[kk] = *(const bf16x8*)(Wbl + woff);
    }
    float bias = Bs[(p*Hc + h)*64 + c0 + l31];
    f32x16 acc;
    #pragma unroll
    for (int i = 0; i < 16; ++i) acc[i] = bias;
    #pragma unroll
    for (int kk = 0; kk < 4; ++kk) {
        acc = mfma32bf(xh[kk], wh[kk], acc);
        acc = mfma32bf(xl[kk], wh[kk], acc);
        acc = mfma32bf(xh[kk], wl[kk], acc);
    }
    const int bh = b*Hc + h;
    if (p < 2) {
        _Float16* dst = (p == 0) ? Qf : Kf;
        #pragma unroll
        for (int r = 0; r < 16; ++r) {
            int row = (r & 3) + 8*(r >> 2) + 4*hi;
            size_t idx = (((size_t)bh*Nc + n0 + r0 + row) << 6) + c0 + l31;
            dst[idx] = (_Float16)acc[r];
        }
    } else {
        // V image granule (kb,o) = V[kb*8..+7][o], fp16
        const int t_img = (n0 + r0) >> 5;
        char* img = (char*)KVimg + (size_t)(bh*96 + t_img)*TILEB;
        #pragma unroll
        for (int grp = 0; grp < 2; ++grp) {
            uint32_t wH[4];
            #pragma unroll
            for (int j = 0; j < 4; ++j)
                wH[j] = pkrtz(acc[grp*8 + 2*j], acc[grp*8 + 2*j + 1]);
            asm("v_permlane32_swap_b32 %0, %1" : "+v"(wH[0]), "+v"(wH[2]));
            asm("v_permlane32_swap_b32 %0, %1" : "+v"(wH[1]), "+v"(wH[3]));
            const int kb = grp*2 + hi;
            const int o  = c0 + l31;
            uint4 gh = {wH[0], wH[1], wH[2], wH[3]};
            *(uint4*)(img + 4096 + ((kb*64 + o) << 4)) = gh;
        }
    }
}

// ---- K image: granule (dc,key) = K[key][dc*8..+7] fp16, at tile offset 0 ----
__global__ void imgk_kernel(const _Float16* __restrict__ Kf, _Float16* __restrict__ KVimg)
{
    const int t = blockIdx.x % 96, bh = blockIdx.x / 96;
    char* img = (char*)KVimg + (size_t)(bh*96 + t)*TILEB;
    int dc = threadIdx.x & 7, key = threadIdx.x >> 3;
    size_t src = (((size_t)bh*Nc + t*32 + key) << 6) + dc*8;
    *(uint4*)(img + (dc*32 + key)*16) = *(const uint4*)(Kf + src);
}

// ---- pack adjacency transposed: pmT[b][w][n], bit j = edge[b][n][32w+j] ----
__global__ void pack_kernel(const int* __restrict__ edge, uint32_t* __restrict__ pmT)
{
    int gw = blockIdx.x*4 + (threadIdx.x >> 6);
    int lane = threadIdx.x & 63;
    int ng = gw % 48; gw /= 48;
    int w  = gw % NW32; gw /= NW32;
    int b  = gw;
    int n = ng*64 + lane;
    const uint4* ep = (const uint4*)(edge + ((size_t)b*Nc + n)*Nc + w*32);
    uint32_t word = 0;
    #pragma unroll
    for (int i = 0; i < 8; ++i) {
        uint4 e = ep[i];
        word |= (e.x ? 1u : 0u) << (4*i);
        word |= (e.y ? 1u : 0u) << (4*i + 1);
        word |= (e.z ? 1u : 0u) << (4*i + 2);
        word |= (e.w ? 1u : 0u) << (4*i + 3);
    }
    pmT[((size_t)b*NW32 + w)*Nc + n] = word;
}

// ---- flash attention fp16: 8 waves = 4 q-groups x 2 key-halves, 16 waves/CU,
//      3-buffer single-barrier pipeline, VALU denominator (no acc2) ----
__global__ __launch_bounds__(512, 4) void attn_mfma(
    const _Float16* __restrict__ Qf,
    const _Float16* __restrict__ KVimg, const uint32_t* __restrict__ pmT,
    float* __restrict__ PA, float* __restrict__ PL)
{
    __shared__ __align__(16) char lds[3][2*TILEB];   // 48 KB
    const int lane = threadIdx.x & 63, w = threadIdx.x >> 6;  // w in [0,8)
    const int l31 = lane & 31, hi = lane >> 5;
    const int p2 = w >> 1;        // q-group
    const int u  = w & 1;         // key-half (32-key subtile)
    int gb = blockIdx.x;
    const int bh = gb & 7; gb >>= 3;        // XCD swizzle: one bh per XCD
    const int qt = gb % 24;
    const int ks = gb / 24;
    const int b = bh >> 2;
    const int qrow0 = qt*128 + p2*32;
    const int t0 = ks*TPS;                  // in 32-key tiles

    // mask pointer for this wave's subtile sequence (tiles t0+u, t0+u+2, ...)
    const uint32_t* pmp = pmT + ((size_t)b*NW32 + t0 + u)*Nc + qrow0 + l31;
    uint32_t mw_cur = pmp[0];
    __builtin_amdgcn_sched_barrier(0);
    const char* gbase = (const char*)KVimg + (size_t)(bh*96 + t0)*TILEB
                      + w*2048 + lane*16;
    #pragma unroll
    for (int g = 0; g < 2; ++g)
        gload_lds16(gbase + g*1024, &lds[0][w*2048 + g*1024]);

    // Q B-frags (col = q-row = l31, k = d), pre-scaled by QSCALE, fp16
    f16x8 qf[4];
    #pragma unroll
    for (int kk = 0; kk < 4; ++kk) {
        size_t qoff = (((size_t)bh*Nc + qrow0 + l31) << 6) + kk*16 + hi*8;
        qf[kk] = *(const f16x8*)(Qf + qoff);
    }
    f32x16 fzero;
    #pragma unroll
    for (int i = 0; i < 16; ++i) fzero[i] = 0.f;

    f32x16 acc0 = fzero, acc1 = fzero;
    float lsum = 0.f;

    #pragma unroll 1
    for (int s = 0; s < 4; ++s) {
        #pragma unroll
        for (int j = 0; j < 3; ++j) {
            // prefetch next pair-tile (always; final one is a harmless in-workspace
            // over-read that is drained before epilogue and never consumed)
            uint32_t mw_next = pmp[(size_t)(j + 1)*2*Nc];
            __builtin_amdgcn_sched_barrier(0);
            {
                char* ldst = &lds[(j + 1) % 3][w*2048];
                const char* gs = gbase + (size_t)(j + 1)*2*TILEB;
                #pragma unroll
                for (int g = 0; g < 2; ++g)
                    gload_lds16(gs + g*1024, ldst + g*1024);
            }
            asm volatile("s_waitcnt vmcnt(3)" ::: "memory");
            __builtin_amdgcn_s_barrier();
            asm volatile("" ::: "memory");   // fence: no LDS reads hoist above barrier
            const char* Lb = &lds[j][u*TILEB];

            // ---- QK^T: 4 MFMA (C=0 seed) ----
            f32x16 sc;
            __builtin_amdgcn_s_setprio(1);
            {
                f16x8 k0 = *(const f16x8*)(Lb + (hi << 9) + (l31 << 4));
                sc = mfma32h(k0, qf[0], fzero);
            }
            #pragma unroll
            for (int kk = 1; kk < 4; ++kk) {
                f16x8 k0 = *(const f16x8*)(Lb + ((kk*2 + hi) << 9) + (l31 << 4));
                sc = mfma32h(k0, qf[kk], sc);
            }
            __builtin_amdgcn_s_setprio(0);

            // ---- softmax -> masked packed fp16 pairs + VALU denominator ----
            uint32_t W8[8];
            softmax_pack(sc, mw_cur >> (hi*4), W8, lsum);
            mw_cur = mw_next;
            f16x8 pa0, pa1;
            assemble_pa(W8, pa0, pa1);

            // ---- PV: 4 MFMA ----
            __builtin_amdgcn_s_setprio(1);
            #pragma unroll
            for (int kkp = 0; kkp < 2; ++kkp) {
                f16x8 pa = kkp ? pa1 : pa0;
                #pragma unroll
                for (int ot = 0; ot < 2; ++ot) {
                    f16x8 vh = *(const f16x8*)(Lb + 4096 + ((kkp*2 + hi) << 10)
                                               + ((ot*32 + l31) << 4));
                    if (ot == 0) acc0 = mfma32h(pa, vh, acc0);
                    else         acc1 = mfma32h(pa, vh, acc1);
                }
            }
            __builtin_amdgcn_s_setprio(0);
            asm volatile("" ::: "memory");   // fence: no LDS reads sink below this iter
        }
        pmp   += (size_t)6*Nc;
        gbase += (size_t)6*TILEB;
    }

    // drain dangling prefetch DMA before reusing LDS for the combine
    asm volatile("s_waitcnt vmcnt(0)" ::: "memory");
    __syncthreads();

    // ---- wave-pair combine (key-halves) via LDS, then store ----
    float* xb  = (float*)&lds[0][0];            // [32][256] floats = 32KB
    float* xl2 = (float*)&lds[0][32*256*4];     // [4][32] lsums
    lsum += __shfl_xor(lsum, 32);               // combine hi halves (16+16 keys)
    if (u) {
        #pragma unroll
        for (int r = 0; r < 16; ++r) {
            xb[(r)      *256 + p2*64 + lane] = acc0[r];
            xb[(16 + r) *256 + p2*64 + lane] = acc1[r];
        }
        if (lane < 32) xl2[p2*32 + l31] = lsum;
    }
    __syncthreads();
    if (!u) {
        #pragma unroll
        for (int r = 0; r < 16; ++r) {
            acc0[r] += xb[(r)      *256 + p2*64 + lane];
            acc1[r] += xb[(16 + r) *256 + p2*64 + lane];
        }
        float* po = PA + (((size_t)(bh*KSC + ks)*Nc + qrow0) << 6);
        #pragma unroll
        for (int r = 0; r < 16; ++r) {
            int row = (r & 3) + 8*(r >> 2) + 4*hi;
            po[((size_t)row << 6) + l31]      = acc0[r];
            po[((size_t)row << 6) + 32 + l31] = acc1[r];
        }
        if (lane < 32) {
            float lt = lsum + xl2[p2*32 + l31];
            PL[(size_t)(bh*KSC + ks)*Nc + qrow0 + l31] = lt;
        }
    }
}

// ---- merge: sum key-splits, divide, mean heads, leaky ----
__global__ void merge_kernel(const float* __restrict__ PA, const float* __restrict__ PL,
                             float* __restrict__ out)
{
    int gid = blockIdx.x*256 + threadIdx.x;
    int o  = gid & 63;
    int bn = gid >> 6;
    int n  = bn % Nc;
    int b  = bn / Nc;
    float ft = 0.f;
    for (int h = 0; h < Hc; ++h) {
        int bh = b*Hc + h;
        float A = 0.f, L = 0.f;
        for (int ks = 0; ks < KSC; ++ks) {
            A += PA[(((size_t)(bh*KSC + ks)*Nc + n) << 6) + o];
            L += PL[(size_t)(bh*KSC + ks)*Nc + n];
        }
        ft += A / L;
    }
    ft *= 0.25f;
    out[((size_t)bn << 6) + o] = fmaxf(ft, 0.f) + 0.2f*fminf(ft, 0.f);
}

extern "C" void kernel_launch(void* const* d_in, const int* in_sizes, int n_in,
                              void* d_out, int out_size, void* d_ws, size_t ws_size,
                              hipStream_t stream)
{
    const float* x    = (const float*)d_in[0];
    const int*   edge = (const int*)d_in[1];
    const float* Wv   = (const float*)d_in[2];
    const float* bv   = (const float*)d_in[3];
    const float* Wq   = (const float*)d_in[4];
    const float* bq   = (const float*)d_in[5];
    const float* Wk   = (const float*)d_in[6];
    const float* bk   = (const float*)d_in[7];
    float* out = (float*)d_out;

    const size_t PROJ = (size_t)Bc*Hc*Nc*64;
    char* p = (char*)d_ws;
    __bf16* Wbh = (__bf16*)p;     p += 49152*2;
    __bf16* Wbl = (__bf16*)p;     p += 49152*2;
    float*  Bs  = (float*)p;      p += 4096;
    _Float16* Qf = (_Float16*)p;  p += PROJ*2;
    _Float16* Kf = (_Float16*)p;  p += PROJ*2;
    _Float16* KVimg = (_Float16*)p; p += (size_t)Bc*Hc*96*TILEB;
    uint32_t* pmT = (uint32_t*)p; p += (size_t)Bc*NW32*Nc*4;
    float* PA = (float*)p;        p += (size_t)Bc*Hc*KSC*Nc*64*4;
    float* PL = (float*)p;

    hipLaunchKernelGGL(prep_kernel, dim3(192),  dim3(256), 0, stream,
                       Wq, Wk, Wv, bq, bk, bv, Wbh, Wbl, Bs);
    hipLaunchKernelGGL(qkv_mfma,    dim3(1152), dim3(256), 0, stream,
                       x, Wbh, Wbl, Bs, Qf, Kf, KVimg);
    hipLaunchKernelGGL(imgk_kernel, dim3(Bc*Hc*96), dim3(256), 0, stream, Kf, KVimg);
    hipLaunchKernelGGL(pack_kernel, dim3(Bc*NW32*48/4), dim3(256), 0, stream, edge, pmT);
    hipLaunchKernelGGL(attn_mfma,   dim3(8*KSC*24), dim3(512), 0, stream,
                       Qf, KVimg, pmT, PA, PL);
    hipLaunchKernelGGL(merge_kernel, dim3((Bc*Nc*64)/256), dim3(256), 0, stream,
                       PA, PL, out);
}